// Round 1
// baseline (1006.894 us; speedup 1.0000x reference)
//
#include <hip/hip_runtime.h>
#include <stdint.h>

// GraphSAGE 2-layer, MI355X.
// Pipeline (linearity: mean_agg(x) @ W == mean_agg(x @ W)):
//   z1 = x@W1l, r1 = x@W1r          (fp32 VALU GEMM, bf16 out)
//   h  = relu(mean_agg(z1) + r1 + b1)   (CSR gather, bf16 out)
//   z2 = h@W2l, r2 = h@W2r          (bf16 in, fp32 VALU GEMM, bf16 out)
//   out = log_softmax(mean_agg(z2) + r2 + b2)   (f32 out)
// CSR built on-device each call: histogram -> 3-pass scan -> scatter.

typedef unsigned int uint32;
typedef unsigned short ushort16;

__device__ __forceinline__ float bf2f(unsigned short u) {
    union { uint32 i; float f; } v; v.i = ((uint32)u) << 16; return v.f;
}
__device__ __forceinline__ unsigned short f2bf(float f) {
    union { float f; uint32 i; } v; v.f = f;
    uint32 i = v.i;
    uint32 r = (i + 0x7FFFu + ((i >> 16) & 1u)) >> 16;  // RNE
    return (unsigned short)r;
}

// ---------------- CSR build ----------------
__global__ void k_degree(const int* __restrict__ dst, int* __restrict__ deg, int E) {
    int stride = gridDim.x * blockDim.x;
    for (int e = blockIdx.x * blockDim.x + threadIdx.x; e < E; e += stride)
        atomicAdd(&deg[dst[e]], 1);
}

__global__ void k_scan1(const int* __restrict__ deg, int* __restrict__ bsum, int n) {
    __shared__ int s[1024];
    int i = blockIdx.x * 1024 + threadIdx.x;
    s[threadIdx.x] = (i < n) ? deg[i] : 0;
    __syncthreads();
    for (int st = 512; st > 0; st >>= 1) {
        if (threadIdx.x < st) s[threadIdx.x] += s[threadIdx.x + st];
        __syncthreads();
    }
    if (threadIdx.x == 0) bsum[blockIdx.x] = s[0];
}

__global__ void k_scan2(int* __restrict__ bsum, int nb) {
    __shared__ int s[128];
    int t = threadIdx.x;
    int v = (t < nb) ? bsum[t] : 0;
    s[t] = v;
    __syncthreads();
    for (int off = 1; off < 128; off <<= 1) {
        int u = (t >= off) ? s[t - off] : 0;
        __syncthreads();
        s[t] += u;
        __syncthreads();
    }
    if (t < nb) bsum[t] = s[t] - v;  // exclusive
}

__global__ void k_scan3(const int* __restrict__ deg, const int* __restrict__ bsum,
                        int* __restrict__ rowstart, int* __restrict__ cursor, int n) {
    __shared__ int s[1024];
    int t = threadIdx.x;
    int i = blockIdx.x * 1024 + t;
    int v = (i < n) ? deg[i] : 0;
    s[t] = v;
    __syncthreads();
    for (int off = 1; off < 1024; off <<= 1) {
        int u = (t >= off) ? s[t - off] : 0;
        __syncthreads();
        s[t] += u;
        __syncthreads();
    }
    int excl = s[t] - v + bsum[blockIdx.x];
    if (i < n) { rowstart[i] = excl; cursor[i] = excl; }
    if (i == n - 1) rowstart[n] = excl + v;   // == E
}

__global__ void k_scatter(const int* __restrict__ src, const int* __restrict__ dst,
                          int* __restrict__ cursor, int* __restrict__ srclist, int E) {
    int stride = gridDim.x * blockDim.x;
    for (int e = blockIdx.x * blockDim.x + threadIdx.x; e < E; e += stride) {
        int d = dst[e];
        int pos = atomicAdd(&cursor[d], 1);
        srclist[pos] = src[e];
    }
}

// ---------------- Layer-1 GEMM: [n,128] x [128,128] -> bf16 ----------------
// grid.y selects (W1l -> z1) or (W1r -> r1). Tile: 64 rows x 128 cols,
// 256 threads, each thread 2 rows x 16 cols. Rows staged in LDS (pad 132:
// bank = (4r+k)%32 -> 2-way, free per m136).
__global__ __launch_bounds__(256) void k_gemm1(const float* __restrict__ x,
        const float* __restrict__ Wl, const float* __restrict__ Wr,
        unsigned short* __restrict__ z, unsigned short* __restrict__ r, int n) {
    __shared__ float X[64][132];
    const float* W = (blockIdx.y == 0) ? Wl : Wr;
    unsigned short* out = (blockIdx.y == 0) ? z : r;
    int rbase = blockIdx.x * 64;

    for (int idx = threadIdx.x; idx < 64 * 32; idx += 256) {
        int rr = idx >> 5, c4 = idx & 31;
        float4 v = make_float4(0.f, 0.f, 0.f, 0.f);
        if (rbase + rr < n) v = ((const float4*)(x + (size_t)(rbase + rr) * 128))[c4];
        *(float4*)&X[rr][c4 * 4] = v;
    }
    __syncthreads();

    int cg = threadIdx.x & 7, rg = threadIdx.x >> 3;
    int c0 = cg * 16, r0 = rg * 2;
    float acc0[16], acc1[16];
#pragma unroll
    for (int j = 0; j < 16; ++j) { acc0[j] = 0.f; acc1[j] = 0.f; }

    for (int k = 0; k < 128; ++k) {
        float a0 = X[r0][k], a1 = X[r0 + 1][k];
        const float4* wrow = (const float4*)(W + (size_t)k * 128 + c0);
#pragma unroll
        for (int q = 0; q < 4; ++q) {
            float4 w = wrow[q];
            acc0[q * 4 + 0] += a0 * w.x; acc0[q * 4 + 1] += a0 * w.y;
            acc0[q * 4 + 2] += a0 * w.z; acc0[q * 4 + 3] += a0 * w.w;
            acc1[q * 4 + 0] += a1 * w.x; acc1[q * 4 + 1] += a1 * w.y;
            acc1[q * 4 + 2] += a1 * w.z; acc1[q * 4 + 3] += a1 * w.w;
        }
    }

#pragma unroll
    for (int rr = 0; rr < 2; ++rr) {
        int row = rbase + r0 + rr;
        if (row < n) {
            const float* a = rr ? acc1 : acc0;
            ushort2* op = (ushort2*)(out + (size_t)row * 128 + c0);
#pragma unroll
            for (int q = 0; q < 8; ++q) {
                ushort2 o; o.x = f2bf(a[2 * q]); o.y = f2bf(a[2 * q + 1]);
                op[q] = o;
            }
        }
    }
}

// ---------------- Layer-1 aggregation + epilogue ----------------
// One wave per node; lane holds 2 channels. h = relu(mean(z1[src]) + r1 + b1).
__global__ __launch_bounds__(256) void k_agg1(const unsigned short* __restrict__ z1,
        const unsigned short* __restrict__ r1, const float* __restrict__ b1,
        const int* __restrict__ rowstart, const int* __restrict__ srclist,
        unsigned short* __restrict__ h, int n) {
    int wid = (blockIdx.x * 256 + threadIdx.x) >> 6;
    int lane = threadIdx.x & 63;
    if (wid >= n) return;
    int s0 = rowstart[wid], s1 = rowstart[wid + 1];
    float ax = 0.f, ay = 0.f;
    for (int j = s0; j < s1; ++j) {
        int src = srclist[j];
        ushort2 u = *(const ushort2*)(z1 + (size_t)src * 128 + lane * 2);
        ax += bf2f(u.x); ay += bf2f(u.y);
    }
    float inv = 1.0f / fmaxf((float)(s1 - s0), 1.0f);
    ushort2 rv = *(const ushort2*)(r1 + (size_t)wid * 128 + lane * 2);
    float2 bv = *(const float2*)(b1 + lane * 2);
    float v0 = fmaxf(ax * inv + bf2f(rv.x) + bv.x, 0.f);
    float v1 = fmaxf(ay * inv + bf2f(rv.y) + bv.y, 0.f);
    ushort2 o; o.x = f2bf(v0); o.y = f2bf(v1);
    *(ushort2*)(h + (size_t)wid * 128 + lane * 2) = o;
}

// ---------------- Layer-2 GEMM: [n,128](bf16) x [128,40] x2 -> bf16 ----------------
// Tile 64 rows; 8 col-groups of 10 cols: groups 0-3 -> W2l/z2, 4-7 -> W2r/r2.
__global__ __launch_bounds__(256) void k_gemm2(const unsigned short* __restrict__ h,
        const float* __restrict__ Wl, const float* __restrict__ Wr,
        unsigned short* __restrict__ z2, unsigned short* __restrict__ r2, int n) {
    __shared__ float X[64][132];
    int rbase = blockIdx.x * 64;

    for (int idx = threadIdx.x; idx < 64 * 32; idx += 256) {
        int rr = idx >> 5, c4 = idx & 31;
        float4 v = make_float4(0.f, 0.f, 0.f, 0.f);
        if (rbase + rr < n) {
            ushort4 u = ((const ushort4*)(h + (size_t)(rbase + rr) * 128))[c4];
            v = make_float4(bf2f(u.x), bf2f(u.y), bf2f(u.z), bf2f(u.w));
        }
        *(float4*)&X[rr][c4 * 4] = v;
    }
    __syncthreads();

    int cg = threadIdx.x & 7, rg = threadIdx.x >> 3;
    const float* W = (cg < 4) ? Wl : Wr;
    unsigned short* out = (cg < 4) ? z2 : r2;
    int cc = (cg & 3) * 10;
    int r0 = rg * 2;
    float acc0[10], acc1[10];
#pragma unroll
    for (int j = 0; j < 10; ++j) { acc0[j] = 0.f; acc1[j] = 0.f; }

    for (int k = 0; k < 128; ++k) {
        float a0 = X[r0][k], a1 = X[r0 + 1][k];
        const float2* wrow = (const float2*)(W + (size_t)k * 40 + cc);
#pragma unroll
        for (int q = 0; q < 5; ++q) {
            float2 w = wrow[q];
            acc0[2 * q + 0] += a0 * w.x; acc0[2 * q + 1] += a0 * w.y;
            acc1[2 * q + 0] += a1 * w.x; acc1[2 * q + 1] += a1 * w.y;
        }
    }

#pragma unroll
    for (int rr = 0; rr < 2; ++rr) {
        int row = rbase + r0 + rr;
        if (row < n) {
            const float* a = rr ? acc1 : acc0;
            ushort2* op = (ushort2*)(out + (size_t)row * 40 + cc);
#pragma unroll
            for (int q = 0; q < 5; ++q) {
                ushort2 o; o.x = f2bf(a[2 * q]); o.y = f2bf(a[2 * q + 1]);
                op[q] = o;
            }
        }
    }
}

// ---------------- Layer-2 aggregation + log_softmax ----------------
// One wave per node; lanes 0..39 hold the 40 output classes.
__global__ __launch_bounds__(256) void k_agg2(const unsigned short* __restrict__ z2,
        const unsigned short* __restrict__ r2, const float* __restrict__ b2,
        const int* __restrict__ rowstart, const int* __restrict__ srclist,
        float* __restrict__ out, int n) {
    int wid = (blockIdx.x * 256 + threadIdx.x) >> 6;
    int lane = threadIdx.x & 63;
    if (wid >= n) return;
    int s0 = rowstart[wid], s1 = rowstart[wid + 1];
    bool act = lane < 40;
    float acc = 0.f;
    for (int j = s0; j < s1; ++j) {
        int src = srclist[j];
        if (act) acc += bf2f(z2[(size_t)src * 40 + lane]);
    }
    float inv = 1.0f / fmaxf((float)(s1 - s0), 1.0f);
    float v = -1e30f;
    if (act) v = acc * inv + bf2f(r2[(size_t)wid * 40 + lane]) + b2[lane];
    float m = v;
#pragma unroll
    for (int off = 32; off > 0; off >>= 1) m = fmaxf(m, __shfl_xor(m, off, 64));
    float e = act ? __expf(v - m) : 0.f;
    float s = e;
#pragma unroll
    for (int off = 32; off > 0; off >>= 1) s += __shfl_xor(s, off, 64);
    if (act) out[(size_t)wid * 40 + lane] = v - m - __logf(s);
}

extern "C" void kernel_launch(void* const* d_in, const int* in_sizes, int n_in,
                              void* d_out, int out_size, void* d_ws, size_t ws_size,
                              hipStream_t stream) {
    const float* x   = (const float*)d_in[0];
    const int*   ei  = (const int*)d_in[1];   // [2][E] int32 (JAX x64 disabled)
    const float* W1l = (const float*)d_in[2];
    const float* W1r = (const float*)d_in[3];
    const float* b1  = (const float*)d_in[4];
    const float* W2l = (const float*)d_in[5];
    const float* W2r = (const float*)d_in[6];
    const float* b2  = (const float*)d_in[7];
    float* out = (float*)d_out;

    int N = in_sizes[0] / 128;
    int E = in_sizes[1] / 2;
    const int* esrc = ei;
    const int* edst = ei + E;

    // workspace carve (256B aligned)
    char* p = (char*)d_ws;
    size_t off = 0;
    auto alloc = [&](size_t bytes) {
        void* q = p + off;
        off = (off + bytes + 255) & ~(size_t)255;
        return q;
    };
    int* deg      = (int*)alloc((size_t)N * 4);
    int* rowstart = (int*)alloc((size_t)(N + 1) * 4);
    int* cursor   = (int*)alloc((size_t)N * 4);
    int* bsum     = (int*)alloc(1024 * 4);
    int* srclist  = (int*)alloc((size_t)E * 4);
    unsigned short* z1 = (unsigned short*)alloc((size_t)N * 128 * 2);
    unsigned short* r1 = (unsigned short*)alloc((size_t)N * 128 * 2);
    unsigned short* hb = (unsigned short*)alloc((size_t)N * 128 * 2);
    // z2/r2 reuse z1's buffer (z1 dead after k_agg1): 2 * N*40 <= N*128
    unsigned short* z2 = z1;
    unsigned short* r2 = z1 + (size_t)N * 40;

    hipMemsetAsync(deg, 0, (size_t)N * 4, stream);
    k_degree<<<2048, 256, 0, stream>>>(edst, deg, E);
    int nb = (N + 1023) / 1024;  // 98 <= 128
    k_scan1<<<nb, 1024, 0, stream>>>(deg, bsum, N);
    k_scan2<<<1, 128, 0, stream>>>(bsum, nb);
    k_scan3<<<nb, 1024, 0, stream>>>(deg, bsum, rowstart, cursor, N);
    k_scatter<<<2048, 256, 0, stream>>>(esrc, edst, cursor, srclist, E);

    dim3 g1((N + 63) / 64, 2);
    k_gemm1<<<g1, 256, 0, stream>>>(x, W1l, W1r, z1, r1, N);
    k_agg1<<<(N + 3) / 4, 256, 0, stream>>>(z1, r1, b1, rowstart, srclist, hb, N);
    k_gemm2<<<(N + 63) / 64, 256, 0, stream>>>(hb, W2l, W2r, z2, r2, N);
    k_agg2<<<(N + 3) / 4, 256, 0, stream>>>(z2, r2, b2, rowstart, srclist, out, N);
}

// Round 2
// 578.544 us; speedup vs baseline: 1.7404x; 1.7404x over previous
//
#include <hip/hip_runtime.h>
#include <stdint.h>

// GraphSAGE 2-layer, MI355X. Round 2: MFMA bf16 GEMMs (register-resident B).
// Pipeline (linearity: mean_agg(x) @ W == mean_agg(x @ W)):
//   prep: Wt1[256][128] bf16 = [W1l|W1r]^T, Wt2[96][128] bf16 = [W2l pad8 | W2r pad8]^T
//   z1|r1 = x @ [W1l|W1r]        (MFMA 16x16x32 bf16, A cvt'd from fp32 on the fly)
//   h  = relu(mean_agg(z1) + r1 + b1)   (CSR gather; h aliases r1 elementwise)
//   z2|r2 = h @ [W2l|W2r]        (MFMA bf16)
//   out = log_softmax(mean_agg(z2) + r2 + b2)
// CSR built on-device each call: histogram -> 3-pass scan -> scatter.

typedef unsigned int uint32;
typedef __bf16 bf16x8 __attribute__((ext_vector_type(8)));
typedef float  f32x4  __attribute__((ext_vector_type(4)));

__device__ __forceinline__ float bf2f(unsigned short u) {
    union { uint32 i; float f; } v; v.i = ((uint32)u) << 16; return v.f;
}
__device__ __forceinline__ unsigned short f2bf(float f) {
    union { float f; uint32 i; } v; v.f = f;
    uint32 i = v.i;
    uint32 r = (i + 0x7FFFu + ((i >> 16) & 1u)) >> 16;  // RNE
    return (unsigned short)r;
}
__device__ __forceinline__ bf16x8 cvt8(float4 a, float4 b) {
    bf16x8 r;
    r[0] = (__bf16)a.x; r[1] = (__bf16)a.y; r[2] = (__bf16)a.z; r[3] = (__bf16)a.w;
    r[4] = (__bf16)b.x; r[5] = (__bf16)b.y; r[6] = (__bf16)b.z; r[7] = (__bf16)b.w;
    return r;
}

// ---------------- CSR build ----------------
__global__ void k_degree(const int* __restrict__ dst, int* __restrict__ deg, int E) {
    int stride = gridDim.x * blockDim.x;
    for (int e = blockIdx.x * blockDim.x + threadIdx.x; e < E; e += stride)
        atomicAdd(&deg[dst[e]], 1);
}

__global__ void k_scan1(const int* __restrict__ deg, int* __restrict__ bsum, int n) {
    __shared__ int s[1024];
    int i = blockIdx.x * 1024 + threadIdx.x;
    s[threadIdx.x] = (i < n) ? deg[i] : 0;
    __syncthreads();
    for (int st = 512; st > 0; st >>= 1) {
        if (threadIdx.x < st) s[threadIdx.x] += s[threadIdx.x + st];
        __syncthreads();
    }
    if (threadIdx.x == 0) bsum[blockIdx.x] = s[0];
}

__global__ void k_scan2(int* __restrict__ bsum, int nb) {
    __shared__ int s[128];
    int t = threadIdx.x;
    int v = (t < nb) ? bsum[t] : 0;
    s[t] = v;
    __syncthreads();
    for (int off = 1; off < 128; off <<= 1) {
        int u = (t >= off) ? s[t - off] : 0;
        __syncthreads();
        s[t] += u;
        __syncthreads();
    }
    if (t < nb) bsum[t] = s[t] - v;  // exclusive
}

__global__ void k_scan3(const int* __restrict__ deg, const int* __restrict__ bsum,
                        int* __restrict__ rowstart, int* __restrict__ cursor, int n) {
    __shared__ int s[1024];
    int t = threadIdx.x;
    int i = blockIdx.x * 1024 + t;
    int v = (i < n) ? deg[i] : 0;
    s[t] = v;
    __syncthreads();
    for (int off = 1; off < 1024; off <<= 1) {
        int u = (t >= off) ? s[t - off] : 0;
        __syncthreads();
        s[t] += u;
        __syncthreads();
    }
    int excl = s[t] - v + bsum[blockIdx.x];
    if (i < n) { rowstart[i] = excl; cursor[i] = excl; }
    if (i == n - 1) rowstart[n] = excl + v;   // == E
}

__global__ void k_scatter(const int* __restrict__ src, const int* __restrict__ dst,
                          int* __restrict__ cursor, int* __restrict__ srclist, int E) {
    int stride = gridDim.x * blockDim.x;
    for (int e = blockIdx.x * blockDim.x + threadIdx.x; e < E; e += stride) {
        int d = dst[e];
        int pos = atomicAdd(&cursor[d], 1);
        srclist[pos] = src[e];
    }
}

// ---------------- weight prep: transpose + bf16 ----------------
// Wt1[c][k], c<128 -> W1l col c; c>=128 -> W1r col c-128. (W is [k][c] row-major.)
__global__ void k_prep_w1(const float* __restrict__ W1l, const float* __restrict__ W1r,
                          unsigned short* __restrict__ Wt1) {
    int idx = blockIdx.x * 256 + threadIdx.x;   // 256*128 total
    int c = idx >> 7, k = idx & 127;
    float v = (c < 128) ? W1l[k * 128 + c] : W1r[k * 128 + (c - 128)];
    Wt1[idx] = f2bf(v);
}
// Wt2[c][k]: c in [0,48) -> W2l col c (0 pad for c>=40); c in [48,96) -> W2r col c-48.
__global__ void k_prep_w2(const float* __restrict__ W2l, const float* __restrict__ W2r,
                          unsigned short* __restrict__ Wt2) {
    int idx = blockIdx.x * 256 + threadIdx.x;   // 96*128 total
    int c = idx >> 7, k = idx & 127;
    const float* W = (c < 48) ? W2l : W2r;
    int cc = (c < 48) ? c : c - 48;
    float v = (cc < 40) ? W[k * 40 + cc] : 0.f;
    Wt2[idx] = f2bf(v);
}

// ---------------- Layer-1 GEMM (MFMA): [n,128]f32 x [128,256]bf16 -> z1|r1 bf16 ----
// Block: 128 rows x 256 cols, 8 waves (512 thr). Wave (w>>2)=rowblk, (w&3)=colblk,
// each wave 64x64 = 4x4 frags of 16x16, K=128 in 4 steps of 32.
// B frags (W) live entirely in registers; A loaded from global fp32, cvt to bf16.
__global__ __launch_bounds__(512) void k_gemm1(const float* __restrict__ x,
        const unsigned short* __restrict__ Wt,
        unsigned short* __restrict__ z1, unsigned short* __restrict__ r1, int N) {
    int lane = threadIdx.x & 63;
    int w    = threadIdx.x >> 6;
    int l15 = lane & 15, g = lane >> 4;
    int rbase = blockIdx.x * 128 + (w >> 2) * 64;
    int cbase = (w & 3) * 64;

    bf16x8 Bf[4][4];
#pragma unroll
    for (int c = 0; c < 4; ++c)
#pragma unroll
        for (int ks = 0; ks < 4; ++ks)
            Bf[c][ks] = *(const bf16x8*)(Wt + (((size_t)(cbase + c * 16 + l15)) << 7)
                                            + ks * 32 + g * 8);

    f32x4 acc[4][4];
    f32x4 z4 = {0.f, 0.f, 0.f, 0.f};
#pragma unroll
    for (int r = 0; r < 4; ++r)
#pragma unroll
        for (int c = 0; c < 4; ++c) acc[r][c] = z4;

#pragma unroll
    for (int ks = 0; ks < 4; ++ks) {
        bf16x8 Af[4];
#pragma unroll
        for (int r = 0; r < 4; ++r) {
            int row = rbase + r * 16 + l15;
            row = row < N ? row : N - 1;          // clamp: no OOB read of input x
            const float* ap = x + (((size_t)row) << 7) + ks * 32 + g * 8;
            float4 lo = *(const float4*)ap;
            float4 hi = *(const float4*)(ap + 4);
            Af[r] = cvt8(lo, hi);
        }
#pragma unroll
        for (int r = 0; r < 4; ++r)
#pragma unroll
            for (int c = 0; c < 4; ++c)
                acc[r][c] = __builtin_amdgcn_mfma_f32_16x16x32_bf16(
                                Af[r], Bf[c][ks], acc[r][c], 0, 0, 0);
    }

    // C/D layout: col = lane&15, row = (lane>>4)*4 + j  [verified m89/m91]
#pragma unroll
    for (int r = 0; r < 4; ++r) {
#pragma unroll
        for (int c = 0; c < 4; ++c) {
            int col = cbase + c * 16 + l15;
            unsigned short* out = (col < 128) ? z1 : r1;
            int cc = col & 127;
#pragma unroll
            for (int j = 0; j < 4; ++j) {
                int row = rbase + r * 16 + g * 4 + j;
                if (row < N) out[((size_t)row << 7) + cc] = f2bf(acc[r][c][j]);
            }
        }
    }
}

// ---------------- Layer-2 GEMM (MFMA): [n,128]bf16 x [128,96]bf16 -> z2|r2 bf16 ----
// Block: 256 rows x 96 cols, 8 waves. Wave (w>>1)=rowblk, (w&1)=half (l/r).
// Each wave 64 rows x 48 cols = 4x3 frags.
__global__ __launch_bounds__(512) void k_gemm2(const unsigned short* __restrict__ hb,
        const unsigned short* __restrict__ Wt2,
        unsigned short* __restrict__ z2, unsigned short* __restrict__ r2, int N) {
    int lane = threadIdx.x & 63;
    int w    = threadIdx.x >> 6;
    int l15 = lane & 15, g = lane >> 4;
    int rbase = blockIdx.x * 256 + (w >> 1) * 64;
    int half  = w & 1;

    bf16x8 Bf[3][4];
#pragma unroll
    for (int c = 0; c < 3; ++c)
#pragma unroll
        for (int ks = 0; ks < 4; ++ks)
            Bf[c][ks] = *(const bf16x8*)(Wt2 + (((size_t)(half * 48 + c * 16 + l15)) << 7)
                                             + ks * 32 + g * 8);

    f32x4 acc[4][3];
    f32x4 z4 = {0.f, 0.f, 0.f, 0.f};
#pragma unroll
    for (int r = 0; r < 4; ++r)
#pragma unroll
        for (int c = 0; c < 3; ++c) acc[r][c] = z4;

#pragma unroll
    for (int ks = 0; ks < 4; ++ks) {
        bf16x8 Af[4];
#pragma unroll
        for (int r = 0; r < 4; ++r) {
            int row = rbase + r * 16 + l15;
            row = row < N ? row : N - 1;
            Af[r] = *(const bf16x8*)(hb + (((size_t)row) << 7) + ks * 32 + g * 8);
        }
#pragma unroll
        for (int r = 0; r < 4; ++r)
#pragma unroll
            for (int c = 0; c < 3; ++c)
                acc[r][c] = __builtin_amdgcn_mfma_f32_16x16x32_bf16(
                                Af[r], Bf[c][ks], acc[r][c], 0, 0, 0);
    }

    unsigned short* out = half ? r2 : z2;
#pragma unroll
    for (int r = 0; r < 4; ++r) {
#pragma unroll
        for (int c = 0; c < 3; ++c) {
            int col = c * 16 + l15;
            if (col < 40) {
#pragma unroll
                for (int j = 0; j < 4; ++j) {
                    int row = rbase + r * 16 + g * 4 + j;
                    if (row < N) out[(size_t)row * 40 + col] = f2bf(acc[r][c][j]);
                }
            }
        }
    }
}

// ---------------- Layer-1 aggregation + epilogue ----------------
// One wave per node; lane holds 2 channels. h = relu(mean(z1[src]) + r1 + b1).
// h aliases r1 (elementwise read-then-write).
__global__ __launch_bounds__(256) void k_agg1(const unsigned short* __restrict__ z1,
        const unsigned short* __restrict__ r1, const float* __restrict__ b1,
        const int* __restrict__ rowstart, const int* __restrict__ srclist,
        unsigned short* __restrict__ h, int n) {
    int wid = (blockIdx.x * 256 + threadIdx.x) >> 6;
    int lane = threadIdx.x & 63;
    if (wid >= n) return;
    int s0 = rowstart[wid], s1 = rowstart[wid + 1];
    float ax = 0.f, ay = 0.f;
    for (int j = s0; j < s1; ++j) {
        int src = srclist[j];
        ushort2 u = *(const ushort2*)(z1 + (size_t)src * 128 + lane * 2);
        ax += bf2f(u.x); ay += bf2f(u.y);
    }
    float inv = 1.0f / fmaxf((float)(s1 - s0), 1.0f);
    ushort2 rv = *(const ushort2*)(r1 + (size_t)wid * 128 + lane * 2);
    float2 bv = *(const float2*)(b1 + lane * 2);
    float v0 = fmaxf(ax * inv + bf2f(rv.x) + bv.x, 0.f);
    float v1 = fmaxf(ay * inv + bf2f(rv.y) + bv.y, 0.f);
    ushort2 o; o.x = f2bf(v0); o.y = f2bf(v1);
    *(ushort2*)(h + (size_t)wid * 128 + lane * 2) = o;
}

// ---------------- Layer-2 aggregation + log_softmax ----------------
__global__ __launch_bounds__(256) void k_agg2(const unsigned short* __restrict__ z2,
        const unsigned short* __restrict__ r2, const float* __restrict__ b2,
        const int* __restrict__ rowstart, const int* __restrict__ srclist,
        float* __restrict__ out, int n) {
    int wid = (blockIdx.x * 256 + threadIdx.x) >> 6;
    int lane = threadIdx.x & 63;
    if (wid >= n) return;
    int s0 = rowstart[wid], s1 = rowstart[wid + 1];
    bool act = lane < 40;
    float acc = 0.f;
    for (int j = s0; j < s1; ++j) {
        int src = srclist[j];
        if (act) acc += bf2f(z2[(size_t)src * 40 + lane]);
    }
    float inv = 1.0f / fmaxf((float)(s1 - s0), 1.0f);
    float v = -1e30f;
    if (act) v = acc * inv + bf2f(r2[(size_t)wid * 40 + lane]) + b2[lane];
    float m = v;
#pragma unroll
    for (int off = 32; off > 0; off >>= 1) m = fmaxf(m, __shfl_xor(m, off, 64));
    float e = act ? __expf(v - m) : 0.f;
    float s = e;
#pragma unroll
    for (int off = 32; off > 0; off >>= 1) s += __shfl_xor(s, off, 64);
    if (act) out[(size_t)wid * 40 + lane] = v - m - __logf(s);
}

extern "C" void kernel_launch(void* const* d_in, const int* in_sizes, int n_in,
                              void* d_out, int out_size, void* d_ws, size_t ws_size,
                              hipStream_t stream) {
    const float* x   = (const float*)d_in[0];
    const int*   ei  = (const int*)d_in[1];   // [2][E] int32 (JAX x64 disabled)
    const float* W1l = (const float*)d_in[2];
    const float* W1r = (const float*)d_in[3];
    const float* b1  = (const float*)d_in[4];
    const float* W2l = (const float*)d_in[5];
    const float* W2r = (const float*)d_in[6];
    const float* b2  = (const float*)d_in[7];
    float* out = (float*)d_out;

    int N = in_sizes[0] / 128;
    int E = in_sizes[1] / 2;
    const int* esrc = ei;
    const int* edst = ei + E;

    // workspace carve (256B aligned)
    char* p = (char*)d_ws;
    size_t off = 0;
    auto alloc = [&](size_t bytes) {
        void* q = p + off;
        off = (off + bytes + 255) & ~(size_t)255;
        return q;
    };
    int* deg      = (int*)alloc((size_t)N * 4);
    int* rowstart = (int*)alloc((size_t)(N + 1) * 4);
    int* cursor   = (int*)alloc((size_t)N * 4);
    int* bsum     = (int*)alloc(1024 * 4);
    unsigned short* Wt1 = (unsigned short*)alloc(256 * 128 * 2);
    unsigned short* Wt2 = (unsigned short*)alloc(96 * 128 * 2);
    int* srclist  = (int*)alloc((size_t)E * 4);
    unsigned short* z1 = (unsigned short*)alloc((size_t)N * 128 * 2);
    unsigned short* r1 = (unsigned short*)alloc((size_t)N * 128 * 2);
    unsigned short* hb = r1;                    // h aliases r1 (elementwise)
    // z2/r2 reuse z1's buffer (z1 dead after k_agg1): 2 * N*40 <= N*128
    unsigned short* z2 = z1;
    unsigned short* r2 = z1 + (size_t)N * 40;

    hipMemsetAsync(deg, 0, (size_t)N * 4, stream);
    k_prep_w1<<<128, 256, 0, stream>>>(W1l, W1r, Wt1);
    k_prep_w2<<<48, 256, 0, stream>>>(W2l, W2r, Wt2);
    k_degree<<<2048, 256, 0, stream>>>(edst, deg, E);
    int nb = (N + 1023) / 1024;  // 98 <= 128
    k_scan1<<<nb, 1024, 0, stream>>>(deg, bsum, N);
    k_scan2<<<1, 128, 0, stream>>>(bsum, nb);
    k_scan3<<<nb, 1024, 0, stream>>>(deg, bsum, rowstart, cursor, N);
    k_scatter<<<2048, 256, 0, stream>>>(esrc, edst, cursor, srclist, E);

    k_gemm1<<<(N + 127) / 128, 512, 0, stream>>>(x, Wt1, z1, r1, N);
    k_agg1<<<(N + 3) / 4, 256, 0, stream>>>(z1, r1, b1, rowstart, srclist, hb, N);
    k_gemm2<<<(N + 255) / 256, 512, 0, stream>>>(hb, Wt2, z2, r2, N);
    k_agg2<<<(N + 3) / 4, 256, 0, stream>>>(z2, r2, b2, rowstart, srclist, out, N);
}

// Round 3
// 369.039 us; speedup vs baseline: 2.7284x; 1.5677x over previous
//
#include <hip/hip_runtime.h>
#include <stdint.h>

// GraphSAGE 2-layer, MI355X. Round 3: wide-gather aggregations.
//   z1|r1 = x @ [W1l|W1r]        (MFMA 16x16x32 bf16, reg-resident B)
//   h  = relu(mean_agg(z1) + r1 + b1)   (4 edges/gather-instr, 16B/lane)
//   z2|r2 = h @ [W2l|W2r]        (MFMA; z2 padded to 64 ch for aligned gathers)
//   out = log_softmax(mean_agg(z2) + r2 + b2)  (8 edges/gather-instr)
// CSR built on-device each call: histogram -> 3-pass scan -> scatter.

typedef unsigned int uint32;
typedef unsigned short u16;
typedef __bf16 bf16x8 __attribute__((ext_vector_type(8)));
typedef float  f32x4  __attribute__((ext_vector_type(4)));
typedef unsigned short u16x8 __attribute__((ext_vector_type(8)));

__device__ __forceinline__ float bf2f(u16 u) {
    union { uint32 i; float f; } v; v.i = ((uint32)u) << 16; return v.f;
}
__device__ __forceinline__ u16 f2bf(float f) {
    union { float f; uint32 i; } v; v.f = f;
    uint32 i = v.i;
    uint32 r = (i + 0x7FFFu + ((i >> 16) & 1u)) >> 16;  // RNE
    return (u16)r;
}
__device__ __forceinline__ bf16x8 cvt8(float4 a, float4 b) {
    bf16x8 r;
    r[0] = (__bf16)a.x; r[1] = (__bf16)a.y; r[2] = (__bf16)a.z; r[3] = (__bf16)a.w;
    r[4] = (__bf16)b.x; r[5] = (__bf16)b.y; r[6] = (__bf16)b.z; r[7] = (__bf16)b.w;
    return r;
}

// ---------------- CSR build ----------------
__global__ void k_degree(const int* __restrict__ dst, int* __restrict__ deg, int E) {
    int t = blockIdx.x * blockDim.x + threadIdx.x;
    int stride = gridDim.x * blockDim.x;
    int e4 = E >> 2;
    for (int i = t; i < e4; i += stride) {
        int4 d = ((const int4*)dst)[i];
        atomicAdd(&deg[d.x], 1); atomicAdd(&deg[d.y], 1);
        atomicAdd(&deg[d.z], 1); atomicAdd(&deg[d.w], 1);
    }
    for (int e = (e4 << 2) + t; e < E; e += stride) atomicAdd(&deg[dst[e]], 1);
}

__global__ void k_scan1(const int* __restrict__ deg, int* __restrict__ bsum, int n) {
    __shared__ int s[1024];
    int i = blockIdx.x * 1024 + threadIdx.x;
    s[threadIdx.x] = (i < n) ? deg[i] : 0;
    __syncthreads();
    for (int st = 512; st > 0; st >>= 1) {
        if (threadIdx.x < st) s[threadIdx.x] += s[threadIdx.x + st];
        __syncthreads();
    }
    if (threadIdx.x == 0) bsum[blockIdx.x] = s[0];
}

__global__ void k_scan2(int* __restrict__ bsum, int nb) {
    __shared__ int s[128];
    int t = threadIdx.x;
    int v = (t < nb) ? bsum[t] : 0;
    s[t] = v;
    __syncthreads();
    for (int off = 1; off < 128; off <<= 1) {
        int u = (t >= off) ? s[t - off] : 0;
        __syncthreads();
        s[t] += u;
        __syncthreads();
    }
    if (t < nb) bsum[t] = s[t] - v;  // exclusive
}

__global__ void k_scan3(const int* __restrict__ deg, const int* __restrict__ bsum,
                        int* __restrict__ rowstart, int* __restrict__ cursor, int n) {
    __shared__ int s[1024];
    int t = threadIdx.x;
    int i = blockIdx.x * 1024 + t;
    int v = (i < n) ? deg[i] : 0;
    s[t] = v;
    __syncthreads();
    for (int off = 1; off < 1024; off <<= 1) {
        int u = (t >= off) ? s[t - off] : 0;
        __syncthreads();
        s[t] += u;
        __syncthreads();
    }
    int excl = s[t] - v + bsum[blockIdx.x];
    if (i < n) { rowstart[i] = excl; cursor[i] = excl; }
    if (i == n - 1) rowstart[n] = excl + v;   // == E
}

__global__ void k_scatter(const int* __restrict__ src, const int* __restrict__ dst,
                          int* __restrict__ cursor, int* __restrict__ srclist, int E) {
    int t = blockIdx.x * blockDim.x + threadIdx.x;
    int stride = gridDim.x * blockDim.x;
    int e4 = E >> 2;
    for (int i = t; i < e4; i += stride) {
        int4 d = ((const int4*)dst)[i];
        int4 s = ((const int4*)src)[i];
        srclist[atomicAdd(&cursor[d.x], 1)] = s.x;
        srclist[atomicAdd(&cursor[d.y], 1)] = s.y;
        srclist[atomicAdd(&cursor[d.z], 1)] = s.z;
        srclist[atomicAdd(&cursor[d.w], 1)] = s.w;
    }
    for (int e = (e4 << 2) + t; e < E; e += stride)
        srclist[atomicAdd(&cursor[dst[e]], 1)] = src[e];
}

// ---------------- weight prep: transpose + bf16 ----------------
__global__ void k_prep_w1(const float* __restrict__ W1l, const float* __restrict__ W1r,
                          u16* __restrict__ Wt1) {
    int idx = blockIdx.x * 256 + threadIdx.x;   // 256*128 total
    int c = idx >> 7, k = idx & 127;
    float v = (c < 128) ? W1l[k * 128 + c] : W1r[k * 128 + (c - 128)];
    Wt1[idx] = f2bf(v);
}
// Wt2[c][k]: c in [0,48) -> W2l col c (0 pad c>=40); c in [48,96) -> W2r col c-48.
__global__ void k_prep_w2(const float* __restrict__ W2l, const float* __restrict__ W2r,
                          u16* __restrict__ Wt2) {
    int idx = blockIdx.x * 256 + threadIdx.x;   // 96*128 total
    int c = idx >> 7, k = idx & 127;
    const float* W = (c < 48) ? W2l : W2r;
    int cc = (c < 48) ? c : c - 48;
    float v = (cc < 40) ? W[k * 40 + cc] : 0.f;
    Wt2[idx] = f2bf(v);
}

// ---------------- Layer-1 GEMM (MFMA): [n,128]f32 x [128,256]bf16 -> z1|r1 bf16 ----
__global__ __launch_bounds__(512) void k_gemm1(const float* __restrict__ x,
        const u16* __restrict__ Wt,
        u16* __restrict__ z1, u16* __restrict__ r1, int N) {
    int lane = threadIdx.x & 63;
    int w    = threadIdx.x >> 6;
    int l15 = lane & 15, g = lane >> 4;
    int rbase = blockIdx.x * 128 + (w >> 2) * 64;
    int cbase = (w & 3) * 64;

    bf16x8 Bf[4][4];
#pragma unroll
    for (int c = 0; c < 4; ++c)
#pragma unroll
        for (int ks = 0; ks < 4; ++ks)
            Bf[c][ks] = *(const bf16x8*)(Wt + (((size_t)(cbase + c * 16 + l15)) << 7)
                                            + ks * 32 + g * 8);

    f32x4 acc[4][4];
    f32x4 z4 = {0.f, 0.f, 0.f, 0.f};
#pragma unroll
    for (int r = 0; r < 4; ++r)
#pragma unroll
        for (int c = 0; c < 4; ++c) acc[r][c] = z4;

#pragma unroll
    for (int ks = 0; ks < 4; ++ks) {
        bf16x8 Af[4];
#pragma unroll
        for (int r = 0; r < 4; ++r) {
            int row = rbase + r * 16 + l15;
            row = row < N ? row : N - 1;          // clamp: no OOB read
            const float* ap = x + (((size_t)row) << 7) + ks * 32 + g * 8;
            float4 lo = *(const float4*)ap;
            float4 hi = *(const float4*)(ap + 4);
            Af[r] = cvt8(lo, hi);
        }
#pragma unroll
        for (int r = 0; r < 4; ++r)
#pragma unroll
            for (int c = 0; c < 4; ++c)
                acc[r][c] = __builtin_amdgcn_mfma_f32_16x16x32_bf16(
                                Af[r], Bf[c][ks], acc[r][c], 0, 0, 0);
    }

    // C/D layout: col = lane&15, row = (lane>>4)*4 + j
#pragma unroll
    for (int r = 0; r < 4; ++r) {
#pragma unroll
        for (int c = 0; c < 4; ++c) {
            int col = cbase + c * 16 + l15;
            u16* out = (col < 128) ? z1 : r1;
            int cc = col & 127;
#pragma unroll
            for (int j = 0; j < 4; ++j) {
                int row = rbase + r * 16 + g * 4 + j;
                if (row < N) out[((size_t)row << 7) + cc] = f2bf(acc[r][c][j]);
            }
        }
    }
}

// ---------------- Layer-2 GEMM (MFMA): [n,128]bf16 x [128,96]bf16 ----
// z2 stored PADDED to 64 cols (cols 40..47 are 0 via Wt2 pad; 48..63 zero-filled).
__global__ __launch_bounds__(512) void k_gemm2(const u16* __restrict__ hb,
        const u16* __restrict__ Wt2,
        u16* __restrict__ z2p, u16* __restrict__ r2, int N) {
    int lane = threadIdx.x & 63;
    int w    = threadIdx.x >> 6;
    int l15 = lane & 15, g = lane >> 4;
    int rbase = blockIdx.x * 256 + (w >> 1) * 64;
    int half  = w & 1;

    bf16x8 Bf[3][4];
#pragma unroll
    for (int c = 0; c < 3; ++c)
#pragma unroll
        for (int ks = 0; ks < 4; ++ks)
            Bf[c][ks] = *(const bf16x8*)(Wt2 + (((size_t)(half * 48 + c * 16 + l15)) << 7)
                                             + ks * 32 + g * 8);

    f32x4 acc[4][3];
    f32x4 z4 = {0.f, 0.f, 0.f, 0.f};
#pragma unroll
    for (int r = 0; r < 4; ++r)
#pragma unroll
        for (int c = 0; c < 3; ++c) acc[r][c] = z4;

#pragma unroll
    for (int ks = 0; ks < 4; ++ks) {
        bf16x8 Af[4];
#pragma unroll
        for (int r = 0; r < 4; ++r) {
            int row = rbase + r * 16 + l15;
            row = row < N ? row : N - 1;
            Af[r] = *(const bf16x8*)(hb + (((size_t)row) << 7) + ks * 32 + g * 8);
        }
#pragma unroll
        for (int r = 0; r < 4; ++r)
#pragma unroll
            for (int c = 0; c < 3; ++c)
                acc[r][c] = __builtin_amdgcn_mfma_f32_16x16x32_bf16(
                                Af[r], Bf[c][ks], acc[r][c], 0, 0, 0);
    }

    if (half == 0) {
        // z2 padded rows: store all 48 computed cols + zero cols 48..63
#pragma unroll
        for (int r = 0; r < 4; ++r)
#pragma unroll
            for (int c = 0; c < 3; ++c) {
                int col = c * 16 + l15;
#pragma unroll
                for (int j = 0; j < 4; ++j) {
                    int row = rbase + r * 16 + g * 4 + j;
                    if (row < N) z2p[((size_t)row << 6) + col] = f2bf(acc[r][c][j]);
                }
            }
        int row = rbase + lane;   // 64 lanes x 64 rows: zero-fill cols 48..63
        if (row < N) {
            u16x8 z8 = {0, 0, 0, 0, 0, 0, 0, 0};
            *(u16x8*)(z2p + ((size_t)row << 6) + 48) = z8;
            *(u16x8*)(z2p + ((size_t)row << 6) + 56) = z8;
        }
    } else {
#pragma unroll
        for (int r = 0; r < 4; ++r)
#pragma unroll
            for (int c = 0; c < 3; ++c) {
                int col = c * 16 + l15;
                if (col < 40) {
#pragma unroll
                    for (int j = 0; j < 4; ++j) {
                        int row = rbase + r * 16 + g * 4 + j;
                        if (row < N) r2[(size_t)row * 40 + col] = f2bf(acc[r][c][j]);
                    }
                }
            }
    }
}

// ---------------- Layer-1 aggregation ----------------
// Wave per node. 4 edges per gather instruction: group g=lane>>4 -> edge,
// c=lane&15 -> 8-ch slice (16B). 2x unrolled. h aliases r1 (elementwise).
__global__ __launch_bounds__(256) void k_agg1(const u16* __restrict__ z1,
        const u16* __restrict__ r1, const float* __restrict__ b1,
        const int* __restrict__ rowstart, const int* __restrict__ srclist,
        u16* __restrict__ h, int n) {
    int wid = (blockIdx.x * 256 + threadIdx.x) >> 6;
    int lane = threadIdx.x & 63;
    if (wid >= n) return;
    int g = lane >> 4, c = lane & 15;
    int s0 = rowstart[wid], s1 = rowstart[wid + 1];
    float acc[8];
#pragma unroll
    for (int i = 0; i < 8; ++i) acc[i] = 0.f;

    int j = s0 + g;
    for (; j + 4 < s1; j += 8) {
        int srcA = srclist[j];
        int srcB = srclist[j + 4];
        u16x8 a = *(const u16x8*)(z1 + ((size_t)srcA << 7) + c * 8);
        u16x8 b = *(const u16x8*)(z1 + ((size_t)srcB << 7) + c * 8);
#pragma unroll
        for (int i = 0; i < 8; ++i) acc[i] += bf2f(a[i]) + bf2f(b[i]);
    }
    if (j < s1) {
        int src = srclist[j];
        u16x8 a = *(const u16x8*)(z1 + ((size_t)src << 7) + c * 8);
#pragma unroll
        for (int i = 0; i < 8; ++i) acc[i] += bf2f(a[i]);
    }
#pragma unroll
    for (int i = 0; i < 8; ++i) {
        acc[i] += __shfl_xor(acc[i], 16, 64);
        acc[i] += __shfl_xor(acc[i], 32, 64);
    }
    if (g == 0) {
        float inv = 1.0f / fmaxf((float)(s1 - s0), 1.0f);
        u16x8 rv = *(const u16x8*)(r1 + ((size_t)wid << 7) + c * 8);
        float4 b0 = *(const float4*)(b1 + c * 8);
        float4 b4 = *(const float4*)(b1 + c * 8 + 4);
        float bb[8] = {b0.x, b0.y, b0.z, b0.w, b4.x, b4.y, b4.z, b4.w};
        u16x8 o;
#pragma unroll
        for (int i = 0; i < 8; ++i)
            o[i] = f2bf(fmaxf(acc[i] * inv + bf2f(rv[i]) + bb[i], 0.f));
        *(u16x8*)(h + ((size_t)wid << 7) + c * 8) = o;
    }
}

// ---------------- Layer-2 aggregation + log_softmax ----------------
// Wave per node. 8 edges per gather: le=lane>>3 -> edge, c=lane&7 -> 8-ch slice
// of the 64-padded z2 row. Epilogue in the le==0 8-lane group.
__global__ __launch_bounds__(256) void k_agg2(const u16* __restrict__ z2p,
        const u16* __restrict__ r2, const float* __restrict__ b2,
        const int* __restrict__ rowstart, const int* __restrict__ srclist,
        float* __restrict__ out, int n) {
    int wid = (blockIdx.x * 256 + threadIdx.x) >> 6;
    int lane = threadIdx.x & 63;
    if (wid >= n) return;
    int le = lane >> 3, c = lane & 7;
    int s0 = rowstart[wid], s1 = rowstart[wid + 1];
    float acc[8];
#pragma unroll
    for (int i = 0; i < 8; ++i) acc[i] = 0.f;

    int j = s0 + le;
    for (; j + 8 < s1; j += 16) {
        int srcA = srclist[j];
        int srcB = srclist[j + 8];
        u16x8 a = *(const u16x8*)(z2p + ((size_t)srcA << 6) + c * 8);
        u16x8 b = *(const u16x8*)(z2p + ((size_t)srcB << 6) + c * 8);
#pragma unroll
        for (int i = 0; i < 8; ++i) acc[i] += bf2f(a[i]) + bf2f(b[i]);
    }
    if (j < s1) {
        int src = srclist[j];
        u16x8 a = *(const u16x8*)(z2p + ((size_t)src << 6) + c * 8);
#pragma unroll
        for (int i = 0; i < 8; ++i) acc[i] += bf2f(a[i]);
    }
#pragma unroll
    for (int i = 0; i < 8; ++i) {
        acc[i] += __shfl_xor(acc[i], 8, 64);
        acc[i] += __shfl_xor(acc[i], 16, 64);
        acc[i] += __shfl_xor(acc[i], 32, 64);
    }
    if (le == 0) {   // lanes 0..7: channels c*8..c*8+7; only c<5 are real (40 ch)
        float inv = 1.0f / fmaxf((float)(s1 - s0), 1.0f);
        bool act = c < 5;
        float v[8];
        if (act) {
            u16x8 rv = *(const u16x8*)(r2 + (size_t)wid * 40 + c * 8);
            float4 b0 = *(const float4*)(b2 + c * 8);
            float4 b4 = *(const float4*)(b2 + c * 8 + 4);
            float bb[8] = {b0.x, b0.y, b0.z, b0.w, b4.x, b4.y, b4.z, b4.w};
#pragma unroll
            for (int i = 0; i < 8; ++i) v[i] = acc[i] * inv + bf2f(rv[i]) + bb[i];
        } else {
#pragma unroll
            for (int i = 0; i < 8; ++i) v[i] = -1e30f;
        }
        float m = v[0];
#pragma unroll
        for (int i = 1; i < 8; ++i) m = fmaxf(m, v[i]);
        m = fmaxf(m, __shfl_xor(m, 1, 64));
        m = fmaxf(m, __shfl_xor(m, 2, 64));
        m = fmaxf(m, __shfl_xor(m, 4, 64));
        float s = 0.f;
        if (act) {
#pragma unroll
            for (int i = 0; i < 8; ++i) s += __expf(v[i] - m);
        }
        s += __shfl_xor(s, 1, 64);
        s += __shfl_xor(s, 2, 64);
        s += __shfl_xor(s, 4, 64);
        float lse = __logf(s);
        if (act) {
            float4 o0, o4;
            o0.x = v[0] - m - lse; o0.y = v[1] - m - lse;
            o0.z = v[2] - m - lse; o0.w = v[3] - m - lse;
            o4.x = v[4] - m - lse; o4.y = v[5] - m - lse;
            o4.z = v[6] - m - lse; o4.w = v[7] - m - lse;
            *(float4*)(out + (size_t)wid * 40 + c * 8) = o0;
            *(float4*)(out + (size_t)wid * 40 + c * 8 + 4) = o4;
        }
    }
}

extern "C" void kernel_launch(void* const* d_in, const int* in_sizes, int n_in,
                              void* d_out, int out_size, void* d_ws, size_t ws_size,
                              hipStream_t stream) {
    const float* x   = (const float*)d_in[0];
    const int*   ei  = (const int*)d_in[1];   // [2][E] int32
    const float* W1l = (const float*)d_in[2];
    const float* W1r = (const float*)d_in[3];
    const float* b1  = (const float*)d_in[4];
    const float* W2l = (const float*)d_in[5];
    const float* W2r = (const float*)d_in[6];
    const float* b2  = (const float*)d_in[7];
    float* out = (float*)d_out;

    int N = in_sizes[0] / 128;
    int E = in_sizes[1] / 2;
    const int* esrc = ei;
    const int* edst = ei + E;

    // workspace carve (256B aligned)
    char* p = (char*)d_ws;
    size_t off = 0;
    auto alloc = [&](size_t bytes) {
        void* q = p + off;
        off = (off + bytes + 255) & ~(size_t)255;
        return q;
    };
    int* deg      = (int*)alloc((size_t)N * 4);
    int* rowstart = (int*)alloc((size_t)(N + 1) * 4);
    int* cursor   = (int*)alloc((size_t)N * 4);
    int* bsum     = (int*)alloc(1024 * 4);
    u16* Wt1 = (u16*)alloc(256 * 128 * 2);
    u16* Wt2 = (u16*)alloc(96 * 128 * 2);
    int* srclist  = (int*)alloc((size_t)E * 4);
    u16* z1 = (u16*)alloc((size_t)N * 128 * 2);
    u16* r1 = (u16*)alloc((size_t)N * 128 * 2);
    u16* hb = r1;                         // h aliases r1 (elementwise)
    // z2p/r2 reuse z1 (dead after k_agg1): N*64 + N*40 <= N*128
    u16* z2p = z1;
    u16* r2  = z1 + (size_t)N * 64;

    hipMemsetAsync(deg, 0, (size_t)N * 4, stream);
    k_prep_w1<<<128, 256, 0, stream>>>(W1l, W1r, Wt1);
    k_prep_w2<<<48, 256, 0, stream>>>(W2l, W2r, Wt2);
    k_degree<<<1024, 256, 0, stream>>>(edst, deg, E);
    int nb = (N + 1023) / 1024;  // 98 <= 128
    k_scan1<<<nb, 1024, 0, stream>>>(deg, bsum, N);
    k_scan2<<<1, 128, 0, stream>>>(bsum, nb);
    k_scan3<<<nb, 1024, 0, stream>>>(deg, bsum, rowstart, cursor, N);
    k_scatter<<<1024, 256, 0, stream>>>(esrc, edst, cursor, srclist, E);

    k_gemm1<<<(N + 127) / 128, 512, 0, stream>>>(x, Wt1, z1, r1, N);
    k_agg1<<<(N + 3) / 4, 256, 0, stream>>>(z1, r1, b1, rowstart, srclist, hb, N);
    k_gemm2<<<(N + 255) / 256, 512, 0, stream>>>(hb, Wt2, z2p, r2, N);
    k_agg2<<<(N + 3) / 4, 256, 0, stream>>>(z2p, r2, b2, rowstart, srclist, out, N);
}

// Round 4
// 341.448 us; speedup vs baseline: 2.9489x; 1.0808x over previous
//
#include <hip/hip_runtime.h>
#include <stdint.h>

// GraphSAGE 2-layer, MI355X. Round 4: XCD-sliced CSR build (write locality).
//   z1|r1 = x @ [W1l|W1r]        (MFMA 16x16x32 bf16, reg-resident B)
//   h  = relu(mean_agg(z1) + r1 + b1)   (4 edges/gather, 16B/lane, 4-deep ILP)
//   z2|r2 = h @ [W2l|W2r]        (MFMA; z2 padded to 64 ch)
//   out = log_softmax(mean_agg(z2) + r2 + b2)  (8 edges/gather)
// CSR build: histogram -> 3-pass scan -> scatter, with degree/scatter sliced
// by dst-range across blockIdx&7 (XCD round-robin heuristic) so cursor+srclist
// stay XCD-L2-resident: random 4B writes merge into full lines before
// writeback (107MB -> ~7MB effective). Correct under ANY block->XCD mapping.

typedef unsigned int uint32;
typedef unsigned short u16;
typedef __bf16 bf16x8 __attribute__((ext_vector_type(8)));
typedef float  f32x4  __attribute__((ext_vector_type(4)));
typedef unsigned short u16x8 __attribute__((ext_vector_type(8)));

__device__ __forceinline__ float bf2f(u16 u) {
    union { uint32 i; float f; } v; v.i = ((uint32)u) << 16; return v.f;
}
__device__ __forceinline__ u16 f2bf(float f) {
    union { float f; uint32 i; } v; v.f = f;
    uint32 i = v.i;
    uint32 r = (i + 0x7FFFu + ((i >> 16) & 1u)) >> 16;  // RNE
    return (u16)r;
}
__device__ __forceinline__ bf16x8 cvt8(float4 a, float4 b) {
    bf16x8 r;
    r[0] = (__bf16)a.x; r[1] = (__bf16)a.y; r[2] = (__bf16)a.z; r[3] = (__bf16)a.w;
    r[4] = (__bf16)b.x; r[5] = (__bf16)b.y; r[6] = (__bf16)b.z; r[7] = (__bf16)b.w;
    return r;
}

// ---------------- CSR build (dst-range sliced) ----------------
// Slice s = blockIdx&7 handles dst in [s*sw, (s+1)*sw). Each slice group
// grid-strides the WHOLE edge list (reads are L2/L3-hits after first touch);
// its atomics+writes land in a per-slice 1/8 region that fits one XCD L2.
__global__ __launch_bounds__(256) void k_degree(const int* __restrict__ dst,
        int* __restrict__ deg, int E, int sw) {
    int s = blockIdx.x & 7, g = blockIdx.x >> 3;
    int lo = s * sw, hi = lo + sw;
    int t = g * 256 + threadIdx.x;
    int stride = (gridDim.x >> 3) * 256;
    int e4 = E >> 2;
    for (int i = t; i < e4; i += stride) {
        int4 d = ((const int4*)dst)[i];
        if (d.x >= lo && d.x < hi) atomicAdd(&deg[d.x], 1);
        if (d.y >= lo && d.y < hi) atomicAdd(&deg[d.y], 1);
        if (d.z >= lo && d.z < hi) atomicAdd(&deg[d.z], 1);
        if (d.w >= lo && d.w < hi) atomicAdd(&deg[d.w], 1);
    }
    for (int e = (e4 << 2) + t; e < E; e += stride) {
        int d = dst[e];
        if (d >= lo && d < hi) atomicAdd(&deg[d], 1);
    }
}

__global__ void k_scan1(const int* __restrict__ deg, int* __restrict__ bsum, int n) {
    __shared__ int s[1024];
    int i = blockIdx.x * 1024 + threadIdx.x;
    s[threadIdx.x] = (i < n) ? deg[i] : 0;
    __syncthreads();
    for (int st = 512; st > 0; st >>= 1) {
        if (threadIdx.x < st) s[threadIdx.x] += s[threadIdx.x + st];
        __syncthreads();
    }
    if (threadIdx.x == 0) bsum[blockIdx.x] = s[0];
}

__global__ void k_scan2(int* __restrict__ bsum, int nb) {
    __shared__ int s[128];
    int t = threadIdx.x;
    int v = (t < nb) ? bsum[t] : 0;
    s[t] = v;
    __syncthreads();
    for (int off = 1; off < 128; off <<= 1) {
        int u = (t >= off) ? s[t - off] : 0;
        __syncthreads();
        s[t] += u;
        __syncthreads();
    }
    if (t < nb) bsum[t] = s[t] - v;  // exclusive
}

__global__ void k_scan3(const int* __restrict__ deg, const int* __restrict__ bsum,
                        int* __restrict__ rowstart, int* __restrict__ cursor, int n) {
    __shared__ int s[1024];
    int t = threadIdx.x;
    int i = blockIdx.x * 1024 + t;
    int v = (i < n) ? deg[i] : 0;
    s[t] = v;
    __syncthreads();
    for (int off = 1; off < 1024; off <<= 1) {
        int u = (t >= off) ? s[t - off] : 0;
        __syncthreads();
        s[t] += u;
        __syncthreads();
    }
    int excl = s[t] - v + bsum[blockIdx.x];
    if (i < n) { rowstart[i] = excl; cursor[i] = excl; }
    if (i == n - 1) rowstart[n] = excl + v;   // == E
}

__global__ __launch_bounds__(256) void k_scatter(const int* __restrict__ src,
        const int* __restrict__ dst, int* __restrict__ cursor,
        int* __restrict__ srclist, int E, int sw) {
    int s = blockIdx.x & 7, g = blockIdx.x >> 3;
    int lo = s * sw, hi = lo + sw;
    int t = g * 256 + threadIdx.x;
    int stride = (gridDim.x >> 3) * 256;
    int e4 = E >> 2;
    for (int i = t; i < e4; i += stride) {
        int4 d = ((const int4*)dst)[i];
        bool any = (d.x >= lo && d.x < hi) || (d.y >= lo && d.y < hi) ||
                   (d.z >= lo && d.z < hi) || (d.w >= lo && d.w < hi);
        if (!any) continue;
        int4 v = ((const int4*)src)[i];
        if (d.x >= lo && d.x < hi) srclist[atomicAdd(&cursor[d.x], 1)] = v.x;
        if (d.y >= lo && d.y < hi) srclist[atomicAdd(&cursor[d.y], 1)] = v.y;
        if (d.z >= lo && d.z < hi) srclist[atomicAdd(&cursor[d.z], 1)] = v.z;
        if (d.w >= lo && d.w < hi) srclist[atomicAdd(&cursor[d.w], 1)] = v.w;
    }
    for (int e = (e4 << 2) + t; e < E; e += stride) {
        int d = dst[e];
        if (d >= lo && d < hi) srclist[atomicAdd(&cursor[d], 1)] = src[e];
    }
}

// ---------------- weight prep: transpose + bf16 (fused w1+w2) ----------------
// blocks [0,128): Wt1 (256 cols x 128 k). blocks [128,176): Wt2 (96 x 128).
__global__ void k_prep(const float* __restrict__ W1l, const float* __restrict__ W1r,
                       const float* __restrict__ W2l, const float* __restrict__ W2r,
                       u16* __restrict__ Wt1, u16* __restrict__ Wt2) {
    if (blockIdx.x < 128) {
        int idx = blockIdx.x * 256 + threadIdx.x;
        int c = idx >> 7, k = idx & 127;
        float v = (c < 128) ? W1l[k * 128 + c] : W1r[k * 128 + (c - 128)];
        Wt1[idx] = f2bf(v);
    } else {
        int idx = (blockIdx.x - 128) * 256 + threadIdx.x;  // 96*128 total
        int c = idx >> 7, k = idx & 127;
        const float* W = (c < 48) ? W2l : W2r;
        int cc = (c < 48) ? c : c - 48;
        float v = (cc < 40) ? W[k * 40 + cc] : 0.f;
        Wt2[idx] = f2bf(v);
    }
}

// ---------------- Layer-1 GEMM (MFMA): [n,128]f32 x [128,256]bf16 -> z1|r1 ----
__global__ __launch_bounds__(512) void k_gemm1(const float* __restrict__ x,
        const u16* __restrict__ Wt,
        u16* __restrict__ z1, u16* __restrict__ r1, int N) {
    int lane = threadIdx.x & 63;
    int w    = threadIdx.x >> 6;
    int l15 = lane & 15, g = lane >> 4;
    int rbase = blockIdx.x * 128 + (w >> 2) * 64;
    int cbase = (w & 3) * 64;

    bf16x8 Bf[4][4];
#pragma unroll
    for (int c = 0; c < 4; ++c)
#pragma unroll
        for (int ks = 0; ks < 4; ++ks)
            Bf[c][ks] = *(const bf16x8*)(Wt + (((size_t)(cbase + c * 16 + l15)) << 7)
                                            + ks * 32 + g * 8);

    f32x4 acc[4][4];
    f32x4 z4 = {0.f, 0.f, 0.f, 0.f};
#pragma unroll
    for (int r = 0; r < 4; ++r)
#pragma unroll
        for (int c = 0; c < 4; ++c) acc[r][c] = z4;

#pragma unroll
    for (int ks = 0; ks < 4; ++ks) {
        bf16x8 Af[4];
#pragma unroll
        for (int r = 0; r < 4; ++r) {
            int row = rbase + r * 16 + l15;
            row = row < N ? row : N - 1;          // clamp: no OOB read
            const float* ap = x + (((size_t)row) << 7) + ks * 32 + g * 8;
            float4 lo = *(const float4*)ap;
            float4 hi = *(const float4*)(ap + 4);
            Af[r] = cvt8(lo, hi);
        }
#pragma unroll
        for (int r = 0; r < 4; ++r)
#pragma unroll
            for (int c = 0; c < 4; ++c)
                acc[r][c] = __builtin_amdgcn_mfma_f32_16x16x32_bf16(
                                Af[r], Bf[c][ks], acc[r][c], 0, 0, 0);
    }

    // C/D layout: col = lane&15, row = (lane>>4)*4 + j
#pragma unroll
    for (int r = 0; r < 4; ++r) {
#pragma unroll
        for (int c = 0; c < 4; ++c) {
            int col = cbase + c * 16 + l15;
            u16* out = (col < 128) ? z1 : r1;
            int cc = col & 127;
#pragma unroll
            for (int j = 0; j < 4; ++j) {
                int row = rbase + r * 16 + g * 4 + j;
                if (row < N) out[((size_t)row << 7) + cc] = f2bf(acc[r][c][j]);
            }
        }
    }
}

// ---------------- Layer-2 GEMM (MFMA): [n,128]bf16 x [128,96]bf16 ----
// z2 stored PADDED to 64 cols (cols 40..47 are 0 via Wt2 pad; 48..63 zero-filled).
__global__ __launch_bounds__(512) void k_gemm2(const u16* __restrict__ hb,
        const u16* __restrict__ Wt2,
        u16* __restrict__ z2p, u16* __restrict__ r2, int N) {
    int lane = threadIdx.x & 63;
    int w    = threadIdx.x >> 6;
    int l15 = lane & 15, g = lane >> 4;
    int rbase = blockIdx.x * 256 + (w >> 1) * 64;
    int half  = w & 1;

    bf16x8 Bf[3][4];
#pragma unroll
    for (int c = 0; c < 3; ++c)
#pragma unroll
        for (int ks = 0; ks < 4; ++ks)
            Bf[c][ks] = *(const bf16x8*)(Wt2 + (((size_t)(half * 48 + c * 16 + l15)) << 7)
                                             + ks * 32 + g * 8);

    f32x4 acc[4][3];
    f32x4 z4 = {0.f, 0.f, 0.f, 0.f};
#pragma unroll
    for (int r = 0; r < 4; ++r)
#pragma unroll
        for (int c = 0; c < 3; ++c) acc[r][c] = z4;

#pragma unroll
    for (int ks = 0; ks < 4; ++ks) {
        bf16x8 Af[4];
#pragma unroll
        for (int r = 0; r < 4; ++r) {
            int row = rbase + r * 16 + l15;
            row = row < N ? row : N - 1;
            Af[r] = *(const bf16x8*)(hb + (((size_t)row) << 7) + ks * 32 + g * 8);
        }
#pragma unroll
        for (int r = 0; r < 4; ++r)
#pragma unroll
            for (int c = 0; c < 3; ++c)
                acc[r][c] = __builtin_amdgcn_mfma_f32_16x16x32_bf16(
                                Af[r], Bf[c][ks], acc[r][c], 0, 0, 0);
    }

    if (half == 0) {
#pragma unroll
        for (int r = 0; r < 4; ++r)
#pragma unroll
            for (int c = 0; c < 3; ++c) {
                int col = c * 16 + l15;
#pragma unroll
                for (int j = 0; j < 4; ++j) {
                    int row = rbase + r * 16 + g * 4 + j;
                    if (row < N) z2p[((size_t)row << 6) + col] = f2bf(acc[r][c][j]);
                }
            }
        int row = rbase + lane;   // zero-fill cols 48..63 of 64 rows
        if (row < N) {
            u16x8 z8 = {0, 0, 0, 0, 0, 0, 0, 0};
            *(u16x8*)(z2p + ((size_t)row << 6) + 48) = z8;
            *(u16x8*)(z2p + ((size_t)row << 6) + 56) = z8;
        }
    } else {
#pragma unroll
        for (int r = 0; r < 4; ++r)
#pragma unroll
            for (int c = 0; c < 3; ++c) {
                int col = c * 16 + l15;
                if (col < 40) {
#pragma unroll
                    for (int j = 0; j < 4; ++j) {
                        int row = rbase + r * 16 + g * 4 + j;
                        if (row < N) r2[(size_t)row * 40 + col] = f2bf(acc[r][c][j]);
                    }
                }
            }
    }
}

// ---------------- Layer-1 aggregation ----------------
// Wave per node. 4 edges per gather: g=lane>>4 -> edge, c=lane&15 -> 16B slice.
// 4-deep load ILP (16 edges in flight). h aliases r1 (elementwise).
__global__ __launch_bounds__(256) void k_agg1(const u16* __restrict__ z1,
        const u16* __restrict__ r1, const float* __restrict__ b1,
        const int* __restrict__ rowstart, const int* __restrict__ srclist,
        u16* __restrict__ h, int n) {
    int wid = (blockIdx.x * 256 + threadIdx.x) >> 6;
    int lane = threadIdx.x & 63;
    if (wid >= n) return;
    int g = lane >> 4, c = lane & 15;
    int s0 = rowstart[wid], s1 = rowstart[wid + 1];
    float acc[8];
#pragma unroll
    for (int i = 0; i < 8; ++i) acc[i] = 0.f;

    int j = s0 + g;
    for (; j + 12 < s1; j += 16) {
        int sA = srclist[j], sB = srclist[j + 4];
        int sC = srclist[j + 8], sD = srclist[j + 12];
        u16x8 a = *(const u16x8*)(z1 + ((size_t)sA << 7) + c * 8);
        u16x8 b = *(const u16x8*)(z1 + ((size_t)sB << 7) + c * 8);
        u16x8 d = *(const u16x8*)(z1 + ((size_t)sC << 7) + c * 8);
        u16x8 e = *(const u16x8*)(z1 + ((size_t)sD << 7) + c * 8);
#pragma unroll
        for (int i = 0; i < 8; ++i)
            acc[i] += (bf2f(a[i]) + bf2f(b[i])) + (bf2f(d[i]) + bf2f(e[i]));
    }
    for (; j + 4 < s1; j += 8) {
        int sA = srclist[j], sB = srclist[j + 4];
        u16x8 a = *(const u16x8*)(z1 + ((size_t)sA << 7) + c * 8);
        u16x8 b = *(const u16x8*)(z1 + ((size_t)sB << 7) + c * 8);
#pragma unroll
        for (int i = 0; i < 8; ++i) acc[i] += bf2f(a[i]) + bf2f(b[i]);
    }
    if (j < s1) {
        int sA = srclist[j];
        u16x8 a = *(const u16x8*)(z1 + ((size_t)sA << 7) + c * 8);
#pragma unroll
        for (int i = 0; i < 8; ++i) acc[i] += bf2f(a[i]);
    }
#pragma unroll
    for (int i = 0; i < 8; ++i) {
        acc[i] += __shfl_xor(acc[i], 16, 64);
        acc[i] += __shfl_xor(acc[i], 32, 64);
    }
    if (g == 0) {
        float inv = 1.0f / fmaxf((float)(s1 - s0), 1.0f);
        u16x8 rv = *(const u16x8*)(r1 + ((size_t)wid << 7) + c * 8);
        float4 b0 = *(const float4*)(b1 + c * 8);
        float4 b4 = *(const float4*)(b1 + c * 8 + 4);
        float bb[8] = {b0.x, b0.y, b0.z, b0.w, b4.x, b4.y, b4.z, b4.w};
        u16x8 o;
#pragma unroll
        for (int i = 0; i < 8; ++i)
            o[i] = f2bf(fmaxf(acc[i] * inv + bf2f(rv[i]) + bb[i], 0.f));
        *(u16x8*)(h + ((size_t)wid << 7) + c * 8) = o;
    }
}

// ---------------- Layer-2 aggregation + log_softmax ----------------
// Wave per node. 8 edges per gather: le=lane>>3 -> edge, c=lane&7 -> 16B slice.
__global__ __launch_bounds__(256) void k_agg2(const u16* __restrict__ z2p,
        const u16* __restrict__ r2, const float* __restrict__ b2,
        const int* __restrict__ rowstart, const int* __restrict__ srclist,
        float* __restrict__ out, int n) {
    int wid = (blockIdx.x * 256 + threadIdx.x) >> 6;
    int lane = threadIdx.x & 63;
    if (wid >= n) return;
    int le = lane >> 3, c = lane & 7;
    int s0 = rowstart[wid], s1 = rowstart[wid + 1];
    float acc[8];
#pragma unroll
    for (int i = 0; i < 8; ++i) acc[i] = 0.f;

    int j = s0 + le;
    for (; j + 8 < s1; j += 16) {
        int sA = srclist[j], sB = srclist[j + 8];
        u16x8 a = *(const u16x8*)(z2p + ((size_t)sA << 6) + c * 8);
        u16x8 b = *(const u16x8*)(z2p + ((size_t)sB << 6) + c * 8);
#pragma unroll
        for (int i = 0; i < 8; ++i) acc[i] += bf2f(a[i]) + bf2f(b[i]);
    }
    if (j < s1) {
        int sA = srclist[j];
        u16x8 a = *(const u16x8*)(z2p + ((size_t)sA << 6) + c * 8);
#pragma unroll
        for (int i = 0; i < 8; ++i) acc[i] += bf2f(a[i]);
    }
#pragma unroll
    for (int i = 0; i < 8; ++i) {
        acc[i] += __shfl_xor(acc[i], 8, 64);
        acc[i] += __shfl_xor(acc[i], 16, 64);
        acc[i] += __shfl_xor(acc[i], 32, 64);
    }
    if (le == 0) {   // lanes 0..7: channels c*8..c*8+7; only c<5 real (40 ch)
        float inv = 1.0f / fmaxf((float)(s1 - s0), 1.0f);
        bool act = c < 5;
        float v[8];
        if (act) {
            u16x8 rv = *(const u16x8*)(r2 + (size_t)wid * 40 + c * 8);
            float4 b0 = *(const float4*)(b2 + c * 8);
            float4 b4 = *(const float4*)(b2 + c * 8 + 4);
            float bb[8] = {b0.x, b0.y, b0.z, b0.w, b4.x, b4.y, b4.z, b4.w};
#pragma unroll
            for (int i = 0; i < 8; ++i) v[i] = acc[i] * inv + bf2f(rv[i]) + bb[i];
        } else {
#pragma unroll
            for (int i = 0; i < 8; ++i) v[i] = -1e30f;
        }
        float m = v[0];
#pragma unroll
        for (int i = 1; i < 8; ++i) m = fmaxf(m, v[i]);
        m = fmaxf(m, __shfl_xor(m, 1, 64));
        m = fmaxf(m, __shfl_xor(m, 2, 64));
        m = fmaxf(m, __shfl_xor(m, 4, 64));
        float s = 0.f;
        if (act) {
#pragma unroll
            for (int i = 0; i < 8; ++i) s += __expf(v[i] - m);
        }
        s += __shfl_xor(s, 1, 64);
        s += __shfl_xor(s, 2, 64);
        s += __shfl_xor(s, 4, 64);
        float lse = __logf(s);
        if (act) {
            float4 o0, o4;
            o0.x = v[0] - m - lse; o0.y = v[1] - m - lse;
            o0.z = v[2] - m - lse; o0.w = v[3] - m - lse;
            o4.x = v[4] - m - lse; o4.y = v[5] - m - lse;
            o4.z = v[6] - m - lse; o4.w = v[7] - m - lse;
            *(float4*)(out + (size_t)wid * 40 + c * 8) = o0;
            *(float4*)(out + (size_t)wid * 40 + c * 8 + 4) = o4;
        }
    }
}

extern "C" void kernel_launch(void* const* d_in, const int* in_sizes, int n_in,
                              void* d_out, int out_size, void* d_ws, size_t ws_size,
                              hipStream_t stream) {
    const float* x   = (const float*)d_in[0];
    const int*   ei  = (const int*)d_in[1];   // [2][E] int32
    const float* W1l = (const float*)d_in[2];
    const float* W1r = (const float*)d_in[3];
    const float* b1  = (const float*)d_in[4];
    const float* W2l = (const float*)d_in[5];
    const float* W2r = (const float*)d_in[6];
    const float* b2  = (const float*)d_in[7];
    float* out = (float*)d_out;

    int N = in_sizes[0] / 128;
    int E = in_sizes[1] / 2;
    const int* esrc = ei;
    const int* edst = ei + E;
    int sw = (N + 7) / 8;   // dst-slice width

    // workspace carve (256B aligned)
    char* p = (char*)d_ws;
    size_t off = 0;
    auto alloc = [&](size_t bytes) {
        void* q = p + off;
        off = (off + bytes + 255) & ~(size_t)255;
        return q;
    };
    int* deg      = (int*)alloc((size_t)N * 4);
    int* rowstart = (int*)alloc((size_t)(N + 1) * 4);
    int* cursor   = (int*)alloc((size_t)N * 4);
    int* bsum     = (int*)alloc(1024 * 4);
    u16* Wt1 = (u16*)alloc(256 * 128 * 2);
    u16* Wt2 = (u16*)alloc(96 * 128 * 2);
    int* srclist  = (int*)alloc((size_t)E * 4);
    u16* z1 = (u16*)alloc((size_t)N * 128 * 2);
    u16* r1 = (u16*)alloc((size_t)N * 128 * 2);
    u16* hb = r1;                         // h aliases r1 (elementwise)
    u16* z2p = z1;                        // reuse z1 (dead after k_agg1)
    u16* r2  = z1 + (size_t)N * 64;

    hipMemsetAsync(deg, 0, (size_t)N * 4, stream);
    k_prep<<<176, 256, 0, stream>>>(W1l, W1r, W2l, W2r, Wt1, Wt2);
    k_degree<<<2048, 256, 0, stream>>>(edst, deg, E, sw);
    int nb = (N + 1023) / 1024;  // 98 <= 128
    k_scan1<<<nb, 1024, 0, stream>>>(deg, bsum, N);
    k_scan2<<<1, 128, 0, stream>>>(bsum, nb);
    k_scan3<<<nb, 1024, 0, stream>>>(deg, bsum, rowstart, cursor, N);
    k_scatter<<<2048, 256, 0, stream>>>(esrc, edst, cursor, srclist, E, sw);

    k_gemm1<<<(N + 127) / 128, 512, 0, stream>>>(x, Wt1, z1, r1, N);
    k_agg1<<<(N + 3) / 4, 256, 0, stream>>>(z1, r1, b1, rowstart, srclist, hb, N);
    k_gemm2<<<(N + 255) / 256, 512, 0, stream>>>(hb, Wt2, z2p, r2, N);
    k_agg2<<<(N + 3) / 4, 256, 0, stream>>>(z2p, r2, b2, rowstart, srclist, out, N);
}